// Round 2
// baseline (227.163 us; speedup 1.0000x reference)
//
#include <hip/hip_runtime.h>

// Problem constants (from reference): BS=16, T=32, Q=1024, logits_b has 2 classes.
#define NFRAMES 512            // BS*T
#define NQ      1024
#define CSIZE   (NFRAMES * NQ) // 524288 floats of cost matrix C

// Fused kernel: one block per frame.
//  - computes C[f, q] for all q and writes it
//  - block-argmin over q (first-occurrence tie-break) -> rows[f]
//  - device-scope atomic bincount of rows
//  - LAST-finishing block computes argmax(bincount) -> mode_idx
__global__ __launch_bounds__(256) void fused_matcher_kernel(
    const float* __restrict__ logits_b,  // [F, Q, 2]
    const float* __restrict__ boxes,     // [F, Q, 4] cxcywh
    const float* __restrict__ tgt,       // [F, 1, 4] cxcywh
    float* __restrict__ out,             // C | rows[F] | mode  (CSIZE+F+1 floats)
    int* __restrict__ bins,              // [NQ]  zeroed before launch
    int* __restrict__ counter)           // [1]   zeroed before launch
{
#pragma clang fp contract(off)
    const int f   = blockIdx.x;
    const int tid = threadIdx.x;

    __shared__ float sv[256];
    __shared__ int   si[256];
    __shared__ int   scc[256];
    __shared__ int   is_last;

    // Target box for this frame (broadcast read).
    const float4 tb = *reinterpret_cast<const float4*>(tgt + (size_t)f * 4);
    const float tx0 = tb.x - 0.5f * tb.z, ty0 = tb.y - 0.5f * tb.w;
    const float tx1 = tb.x + 0.5f * tb.z, ty1 = tb.y + 0.5f * tb.w;
    const float area2 = (tx1 - tx0) * (ty1 - ty0);

    const float* fb = boxes    + (size_t)f * NQ * 4;
    const float* fl = logits_b + (size_t)f * NQ * 2;
    float*       fc = out      + (size_t)f * NQ;

    float bestv = INFINITY;
    int   besti = 0;

    #pragma unroll
    for (int k = 0; k < 4; ++k) {
        const int q = tid + k * 256;   // ascending per-thread order => strict < keeps first min
        const float4 pb = *reinterpret_cast<const float4*>(fb + q * 4);
        const float2 lg = *reinterpret_cast<const float2*>(fl + q * 2);

        // cost_bbox: L1 on raw cxcywh
        const float cb = fabsf(pb.x - tb.x) + fabsf(pb.y - tb.y)
                       + fabsf(pb.z - tb.z) + fabsf(pb.w - tb.w);

        // cxcywh -> xyxy (same expression order as reference)
        const float px0 = pb.x - 0.5f * pb.z, py0 = pb.y - 0.5f * pb.w;
        const float px1 = pb.x + 0.5f * pb.z, py1 = pb.y + 0.5f * pb.w;
        const float area1 = (px1 - px0) * (py1 - py0);

        const float ltx = fmaxf(px0, tx0), lty = fmaxf(py0, ty0);
        const float rbx = fminf(px1, tx1), rby = fminf(py1, ty1);
        const float whx = fmaxf(rbx - ltx, 0.0f), why = fmaxf(rby - lty, 0.0f);
        const float inter = whx * why;
        const float uni   = area1 + area2 - inter;
        const float iou   = inter / uni;

        const float lcx = fminf(px0, tx0), lcy = fminf(py0, ty0);
        const float rcx = fmaxf(px1, tx1), rcy = fmaxf(py1, ty1);
        const float wcx = fmaxf(rcx - lcx, 0.0f), wcy = fmaxf(rcy - lcy, 0.0f);
        const float areac = wcx * wcy;
        const float giou  = iou - (areac - uni) / areac;
        const float cg    = -giou;

        // cost_class: -softmax(lg)[1], max-subtracted like jax.nn.softmax
        const float m  = fmaxf(lg.x, lg.y);
        const float e0 = expf(lg.x - m), e1 = expf(lg.y - m);
        const float cc = -(e1 / (e0 + e1));

        const float c = 5.0f * cb + 1.0f * cc + 2.0f * cg;
        fc[q] = c;

        if (c < bestv) { bestv = c; besti = q; }
    }

    // Block argmin reduce, first-occurrence tie-break (smaller idx on equal val).
    sv[tid] = bestv; si[tid] = besti;
    __syncthreads();
    for (int s = 128; s > 0; s >>= 1) {
        if (tid < s) {
            const float v2 = sv[tid + s];
            const int   i2 = si[tid + s];
            if (v2 < sv[tid] || (v2 == sv[tid] && i2 < si[tid])) { sv[tid] = v2; si[tid] = i2; }
        }
        __syncthreads();
    }

    if (tid == 0) {
        const int row = si[0];
        out[CSIZE + f] = (float)row;
        atomicAdd(&bins[row], 1);            // device-scope (cross-XCD safe)
        __threadfence();                     // release rows/bins before counter bump
        const int old = __hip_atomic_fetch_add(counter, 1, __ATOMIC_ACQ_REL,
                                               __HIP_MEMORY_SCOPE_AGENT);
        is_last = (old == NFRAMES - 1) ? 1 : 0;
    }
    __syncthreads();

    if (is_last) {
        // argmax over 1024 bins; thread tid owns bins [tid*4, tid*4+4) (contiguous,
        // ascending => strict > keeps first occurrence overall after the reduce).
        int bc = -1, bi = 0;
        #pragma unroll
        for (int k = 0; k < 4; ++k) {
            const int i = tid * 4 + k;
            const int c = __hip_atomic_load(&bins[i], __ATOMIC_RELAXED,
                                            __HIP_MEMORY_SCOPE_AGENT);
            if (c > bc) { bc = c; bi = i; }
        }
        scc[tid] = bc; si[tid] = bi;
        __syncthreads();
        for (int s = 128; s > 0; s >>= 1) {
            if (tid < s) {
                const int c2 = scc[tid + s];
                const int i2 = si[tid + s];
                if (c2 > scc[tid] || (c2 == scc[tid] && i2 < si[tid])) {
                    scc[tid] = c2; si[tid] = i2;
                }
            }
            __syncthreads();
        }
        if (tid == 0) out[CSIZE + NFRAMES] = (float)si[0];
    }
}

extern "C" void kernel_launch(void* const* d_in, const int* in_sizes, int n_in,
                              void* d_out, int out_size, void* d_ws, size_t ws_size,
                              hipStream_t stream) {
    // d_in[0] = pred_logits   (UNUSED by the computation)
    // d_in[1] = pred_logits_b [16,32,1024,2] f32
    // d_in[2] = pred_boxes    [16,32,1024,4] f32
    // d_in[3] = tgt_bbox      [16,32,1,4]    f32
    // d_in[4] = tgt_ids       (UNUSED)
    const float* logits_b = (const float*)d_in[1];
    const float* boxes    = (const float*)d_in[2];
    const float* tgt      = (const float*)d_in[3];
    float* out   = (float*)d_out;
    int*   bins  = (int*)d_ws;          // [NQ]
    int*   cnt   = bins + NQ;           // [1]

    // d_ws is poisoned to 0xAA before every call — zero our scratch (capture-safe).
    hipMemsetAsync(d_ws, 0, (NQ + 1) * sizeof(int), stream);

    hipLaunchKernelGGL(fused_matcher_kernel, dim3(NFRAMES), dim3(256), 0, stream,
                       logits_b, boxes, tgt, out, bins, cnt);
}

// Round 3
// 209.024 us; speedup vs baseline: 1.0868x; 1.0868x over previous
//
#include <hip/hip_runtime.h>

// Problem constants (from reference): BS=16, T=32, Q=1024, logits_b has 2 classes.
#define NFRAMES 512            // BS*T
#define NQ      1024
#define CSIZE   (NFRAMES * NQ) // 524288 floats of cost matrix C

// Kernel A: one block per frame. Computes C[f, q] for all q, writes it to out,
// and reduces argmin over q (first-occurrence tie-break) -> rows[f].
__global__ __launch_bounds__(256) void cost_argmin_kernel(
    const float* __restrict__ logits_b,  // [F, Q, 2]
    const float* __restrict__ boxes,     // [F, Q, 4] cxcywh
    const float* __restrict__ tgt,       // [F, 1, 4] cxcywh
    float* __restrict__ out)             // C at [0,CSIZE), rows at [CSIZE, CSIZE+F)
{
#pragma clang fp contract(off)
    const int f   = blockIdx.x;
    const int tid = threadIdx.x;

    // Target box for this frame (broadcast read; L1-cached).
    const float4 tb = *reinterpret_cast<const float4*>(tgt + (size_t)f * 4);
    const float tx0 = tb.x - 0.5f * tb.z, ty0 = tb.y - 0.5f * tb.w;
    const float tx1 = tb.x + 0.5f * tb.z, ty1 = tb.y + 0.5f * tb.w;
    const float area2 = (tx1 - tx0) * (ty1 - ty0);

    const float* fb = boxes    + (size_t)f * NQ * 4;
    const float* fl = logits_b + (size_t)f * NQ * 2;
    float*       fc = out      + (size_t)f * NQ;

    float bestv = INFINITY;
    int   besti = 0;

    #pragma unroll
    for (int k = 0; k < 4; ++k) {
        const int q = tid + k * 256;   // ascending per-thread order => strict < keeps first min
        const float4 pb = *reinterpret_cast<const float4*>(fb + q * 4);
        const float2 lg = *reinterpret_cast<const float2*>(fl + q * 2);

        // cost_bbox: L1 on raw cxcywh
        const float cb = fabsf(pb.x - tb.x) + fabsf(pb.y - tb.y)
                       + fabsf(pb.z - tb.z) + fabsf(pb.w - tb.w);

        // cxcywh -> xyxy (same expression order as reference)
        const float px0 = pb.x - 0.5f * pb.z, py0 = pb.y - 0.5f * pb.w;
        const float px1 = pb.x + 0.5f * pb.z, py1 = pb.y + 0.5f * pb.w;
        const float area1 = (px1 - px0) * (py1 - py0);

        const float ltx = fmaxf(px0, tx0), lty = fmaxf(py0, ty0);
        const float rbx = fminf(px1, tx1), rby = fminf(py1, ty1);
        const float whx = fmaxf(rbx - ltx, 0.0f), why = fmaxf(rby - lty, 0.0f);
        const float inter = whx * why;
        const float uni   = area1 + area2 - inter;
        const float iou   = inter / uni;

        const float lcx = fminf(px0, tx0), lcy = fminf(py0, ty0);
        const float rcx = fmaxf(px1, tx1), rcy = fmaxf(py1, ty1);
        const float wcx = fmaxf(rcx - lcx, 0.0f), wcy = fmaxf(rcy - lcy, 0.0f);
        const float areac = wcx * wcy;
        const float giou  = iou - (areac - uni) / areac;
        const float cg    = -giou;

        // cost_class: -softmax(lg)[1], max-subtracted like jax.nn.softmax
        const float m  = fmaxf(lg.x, lg.y);
        const float e0 = expf(lg.x - m), e1 = expf(lg.y - m);
        const float cc = -(e1 / (e0 + e1));

        const float c = 5.0f * cb + 1.0f * cc + 2.0f * cg;
        fc[q] = c;

        if (c < bestv) { bestv = c; besti = q; }
    }

    // Block argmin reduce, first-occurrence tie-break (smaller idx on equal val).
    __shared__ float sv[256];
    __shared__ int   si[256];
    sv[tid] = bestv; si[tid] = besti;
    __syncthreads();
    for (int s = 128; s > 0; s >>= 1) {
        if (tid < s) {
            const float v2 = sv[tid + s];
            const int   i2 = si[tid + s];
            if (v2 < sv[tid] || (v2 == sv[tid] && i2 < si[tid])) { sv[tid] = v2; si[tid] = i2; }
        }
        __syncthreads();
    }
    if (tid == 0) out[CSIZE + f] = (float)si[0];
}

// Kernel B: bincount(rows, length=1024) + argmax (first-occurrence tie-break).
// One block of 512 threads: thread f reads rows[f]; argmax over 1024 bins with
// 2 contiguous bins per thread.
__global__ __launch_bounds__(512) void mode_kernel(float* __restrict__ out)
{
    __shared__ int counts[NQ];
    __shared__ int sc[512];
    __shared__ int si[512];
    const int tid = threadIdx.x;

    counts[tid] = 0;
    counts[tid + 512] = 0;
    __syncthreads();
    const int r = (int)out[CSIZE + tid];   // tid in [0,512) == frame idx
    atomicAdd(&counts[r], 1);
    __syncthreads();

    // Thread tid owns bins {2*tid, 2*tid+1} (contiguous ascending => first-occurrence
    // tie-break preserved: local strict >, cross-thread smaller idx on equal count).
    const int c0 = counts[2 * tid];
    const int c1 = counts[2 * tid + 1];
    int bc, bi;
    if (c1 > c0) { bc = c1; bi = 2 * tid + 1; } else { bc = c0; bi = 2 * tid; }
    sc[tid] = bc; si[tid] = bi;
    __syncthreads();
    for (int s = 256; s > 0; s >>= 1) {
        if (tid < s) {
            const int c2 = sc[tid + s];
            const int i2 = si[tid + s];
            if (c2 > sc[tid] || (c2 == sc[tid] && i2 < si[tid])) { sc[tid] = c2; si[tid] = i2; }
        }
        __syncthreads();
    }
    if (tid == 0) out[CSIZE + NFRAMES] = (float)si[0];
}

extern "C" void kernel_launch(void* const* d_in, const int* in_sizes, int n_in,
                              void* d_out, int out_size, void* d_ws, size_t ws_size,
                              hipStream_t stream) {
    // d_in[0] = pred_logits   (UNUSED by the computation)
    // d_in[1] = pred_logits_b [16,32,1024,2] f32
    // d_in[2] = pred_boxes    [16,32,1024,4] f32
    // d_in[3] = tgt_bbox      [16,32,1,4]    f32
    // d_in[4] = tgt_ids       (UNUSED)
    const float* logits_b = (const float*)d_in[1];
    const float* boxes    = (const float*)d_in[2];
    const float* tgt      = (const float*)d_in[3];
    float* out = (float*)d_out;

    hipLaunchKernelGGL(cost_argmin_kernel, dim3(NFRAMES), dim3(256), 0, stream,
                       logits_b, boxes, tgt, out);
    hipLaunchKernelGGL(mode_kernel, dim3(1), dim3(512), 0, stream, out);
}